// Round 11
// baseline (215.786 us; speedup 1.0000x reference)
//
#include <hip/hip_runtime.h>
#include <math.h>

#define IN_UNITS 1152
#define OUT_UNITS 32
#define BATCH 64
#define NCHK 24            // i-chunks; 24%8==0 -> chunk c on XCD c%8 (grid-linear)
#define IPB 48             // i's per chunk
#define NG 12              // g-steps; 4 i per step, 2 b per block (il-split)
#define PREC 33            // values per (chunk,o): S, mu[16], v2[16]
#define PBLK (PREC*OUT_UNITS)   // 1056 floats, layout [j][o] (o-minor)

// thread layout: o = t&31, il = t>>5 (0..7); ilq = il&3 picks i, bb = il>>2
// picks batch. Waves {0,1} = b0, waves {2,3} = b1; waves 0 and 2 load the
// SAME W lines (L1 dedup -> W L2 traffic halved). lanes l, l^32 share o and b.
// MODE 0: R = a/32, reads original-layout W, (bq==0,bb==0) threads emit Wt.
// MODE 1: R-update (softmax over o) + stats, reads transposed Wt (coalesced).
template<int MODE>
__global__ __launch_bounds__(256, 4) void caps_main(
    const float* __restrict__ a_in, const float* __restrict__ Mm,
    const float* __restrict__ Wg, const float4* __restrict__ Wt4,
    float4* __restrict__ Wt4w,
    const float* __restrict__ mu_g, const float* __restrict__ i2v_g,
    const float* __restrict__ lae_g,
    float* __restrict__ part)
{
    const int t = threadIdx.x, o = t & 31, il = t >> 5;
    const int ilq = il & 3, bb = il >> 2, wv = t >> 6, lane = t & 63;
    const int c = blockIdx.x, bq = blockIdx.y;
    const int b = bq*2 + bb;
    const int i0 = c*IPB;

    __shared__ float sRed[4][PBLK];   // 16.9 KB

    // routing state for (b, o) in registers (per-thread, no LDS, no barrier)
    float rmu[16], ri2[16], lae = 0.f;
    if (MODE) {
        #pragma unroll
        for (int k = 0; k < 16; ++k) {
            rmu[k] = mu_g[b*512 + k*32 + o];    // coalesced rows of 32
            ri2[k] = i2v_g[b*512 + k*32 + o];
        }
        lae = lae_g[b*32 + o];                  // log a + log eff
    }

    const float4* mbase = (const float4*)Mm + (b*IN_UNITS + i0 + ilq)*4;  // +g*16 +x
    const float*  abase = a_in + b*IN_UNITS + i0 + ilq;                   // +g*4

    float pS = 0.f, pmu[16], pv2[16];
    #pragma unroll
    for (int k = 0; k < 16; ++k) { pmu[k] = 0.f; pv2[k] = 0.f; }

    #pragma unroll
    for (int g = 0; g < NG; ++g) {
        const int i = i0 + g*4 + ilq;

        float w[16];
        if (MODE == 0) {
            // original W[i][o][ch]: 64B per (i,o); y=0 fetches the 2KB span,
            // y=1..3 hit L1. One-time cost.
            const float4* wp = (const float4*)(Wg + i*512 + o*16);
            #pragma unroll
            for (int y = 0; y < 4; ++y) *(float4*)&w[y*4] = wp[y];
            if (bq == 0 && bb == 0) {   // emit Wt[i][y][o][z] (coalesced)
                #pragma unroll
                for (int y = 0; y < 4; ++y)
                    Wt4w[(i*4 + y)*32 + o] = *(const float4*)&w[y*4];
            }
        } else {
            const float4* wp = Wt4 + (i*4)*32 + o;   // 512B/inst, coalesced
            #pragma unroll
            for (int y = 0; y < 4; ++y) *(float4*)&w[y*4] = wp[y*32];
        }

        float Mr[16];   // 64B row broadcast to 32 lanes via L1
        #pragma unroll
        for (int x = 0; x < 4; ++x) *(float4*)&Mr[x*4] = mbase[g*16 + x];
        const float a_val = abase[g*4];

        float v[16];
        #pragma unroll
        for (int x = 0; x < 4; ++x)
            #pragma unroll
            for (int z = 0; z < 4; ++z) {
                float acc = 0.f;
                #pragma unroll
                for (int y = 0; y < 4; ++y)
                    acc = fmaf(Mr[x*4 + y], w[y*4 + z], acc);
                v[x*4 + z] = acc;
            }

        float wgt;
        if (MODE == 0) {
            wgt = a_val * (1.0f/32.0f);          // R0 = 1/32
        } else {
            float ex0 = 0.f, ex1 = 0.f;
            #pragma unroll
            for (int k = 0; k < 16; k += 2) {
                float d0 = v[k]   - rmu[k];
                float d1 = v[k+1] - rmu[k+1];
                ex0 = fmaf(d0*d0, ri2[k],   ex0);
                ex1 = fmaf(d1*d1, ri2[k+1], ex1);
            }
            float e = __expf(lae - (ex0 + ex1)); // a*eff*exp(exponent)
            float s = e;
            #pragma unroll
            for (int m = 16; m >= 1; m >>= 1) s += __shfl_xor(s, m);
            wgt = (e / s) * a_val;               // R over o, * input_a
        }

        pS += wgt;
        #pragma unroll
        for (int k = 0; k < 16; ++k) {
            pmu[k] = fmaf(wgt, v[k], pmu[k]);
            pv2[k] = fmaf(wgt*v[k], v[k], pv2[k]);
        }
    }

    // lanes l <-> l^32: same o, same b, adjacent il -> combine
    pS += __shfl_xor(pS, 32);
    #pragma unroll
    for (int k = 0; k < 16; ++k) {
        pmu[k] += __shfl_xor(pmu[k], 32);
        pv2[k] += __shfl_xor(pv2[k], 32);
    }
    if (lane < 32) {   // [j][o] layout: conflict-free, coalesced downstream
        float* r = &sRed[wv][0];
        r[o] = pS;
        #pragma unroll
        for (int k = 0; k < 16; ++k) {
            r[(1+k)*32 + o]  = pmu[k];
            r[(17+k)*32 + o] = pv2[k];
        }
    }
    __syncthreads();
    // rows 0,1 = b0 (waves 0,1); rows 2,3 = b1 (waves 2,3)
    float* dst0 = part + ((bq*2 + 0)*NCHK + c)*PBLK;
    float* dst1 = part + ((bq*2 + 1)*NCHK + c)*PBLK;
    for (int idx = t; idx < PBLK; idx += 256) {
        dst0[idx] = sRed[0][idx] + sRed[1][idx];
        dst1[idx] = sRed[2][idx] + sRed[3][idx];
    }
}

// finalize: one block per b reduces its 24 chunk-partials (seg handles 3)
__global__ __launch_bounds__(256) void caps_fin(
    const float* __restrict__ part,
    const float* __restrict__ beta_u, const float* __restrict__ beta_a,
    float* __restrict__ mu_g, float* __restrict__ i2v_g, float* __restrict__ lae_g,
    float lamb, float* __restrict__ out)
{
    const int b = blockIdx.x;
    const int t = threadIdx.x;
    const int o = t & 31;
    const int seg = t >> 5;

    float S = 0.f, m[16], q[16];
    #pragma unroll
    for (int k = 0; k < 16; ++k) { m[k] = 0.f; q[k] = 0.f; }
    #pragma unroll
    for (int cc = 0; cc < 3; ++cc) {
        const float* p = part + (b*NCHK + seg + cc*8)*PBLK;
        S += p[o];
        #pragma unroll
        for (int k = 0; k < 16; ++k) {
            m[k] += p[(1+k)*32 + o];
            q[k] += p[(17+k)*32 + o];
        }
    }

    __shared__ float sF[8][PBLK];
    {
        float* r = &sF[seg][0];
        r[o] = S;
        #pragma unroll
        for (int k = 0; k < 16; ++k) { r[(1+k)*32+o] = m[k]; r[(17+k)*32+o] = q[k]; }
    }
    __syncthreads();
    if (t < 32) {
        #pragma unroll
        for (int s = 1; s < 8; ++s) {
            const float* r = &sF[s][0];
            S += r[o];
            #pragma unroll
            for (int k = 0; k < 16; ++k) { m[k] += r[(1+k)*32+o]; q[k] += r[(17+k)*32+o]; }
        }
        const float invS = 1.f / S;
        float mu[16], logvarsum = 0.f;
        #pragma unroll
        for (int k = 0; k < 16; ++k) {
            mu[k] = m[k] * invS;
            float vv = q[k]*invS - mu[k]*mu[k];   // E[v^2] - mu^2
            vv = fmaxf(vv, 1e-30f);
            q[k] = vv;                            // var
            logvarsum += logf(vv);
        }
        const float cost = S * (16.f*beta_u[o] + 0.5f*logvarsum);
        const float x = lamb * (beta_a[o] - cost);
        const float log_a = (x >= 0.f) ? -log1pf(expf(-x)) : (x - log1pf(expf(x)));
        const float LOG2PI = 1.8378770664093453f;
        const float logeff = 16.f*LOG2PI + logvarsum;

        const int tid = b*32 + o;
        lae_g[tid] = log_a + logeff;
        #pragma unroll
        for (int k = 0; k < 16; ++k) {
            mu_g[b*512 + k*32 + o]  = mu[k];
            i2v_g[b*512 + k*32 + o] = 0.5f / q[k];
        }
        if (out) {
            out[tid] = 1.f / (1.f + expf(-x));                      // a (64,32)
            #pragma unroll
            for (int k = 0; k < 16; ++k)
                out[BATCH*OUT_UNITS + tid*16 + k] = mu[k];          // mu (64,32,16)
        }
    }
}

extern "C" void kernel_launch(void* const* d_in, const int* in_sizes, int n_in,
                              void* d_out, int out_size, void* d_ws, size_t ws_size,
                              hipStream_t stream)
{
    const float* a_in = (const float*)d_in[0];
    const float* Mm   = (const float*)d_in[1];
    const float* Wg   = (const float*)d_in[2];
    const float* bu   = (const float*)d_in[3];
    const float* ba   = (const float*)d_in[4];
    float* out = (float*)d_out;

    char* ws = (char*)d_ws;
    size_t off = 0;
    float* part  = (float*)(ws + off); off += (size_t)BATCH*NCHK*PBLK*sizeof(float);
    float* mu_g  = (float*)(ws + off); off += (size_t)BATCH*512*sizeof(float);
    float* i2v_g = (float*)(ws + off); off += (size_t)BATCH*512*sizeof(float);
    float* lae_g = (float*)(ws + off); off += (size_t)BATCH*32*sizeof(float);
    float* Wt    = (float*)(ws + off); off += (size_t)IN_UNITS*OUT_UNITS*16*sizeof(float);

    dim3 grid(NCHK, BATCH/2), blk(256);
    const float4* Wt4 = (const float4*)Wt;
    float4* Wt4w = (float4*)Wt;

    // it 0: stats under R = a/32 (reads original W, emits Wt)
    caps_main<0><<<grid, blk, 0, stream>>>(a_in, Mm, Wg, nullptr, Wt4w,
                                           nullptr, nullptr, nullptr, part);
    caps_fin<<<BATCH, 256, 0, stream>>>(part, bu, ba, mu_g, i2v_g, lae_g, 0.01f, nullptr);
    // it 1
    caps_main<1><<<grid, blk, 0, stream>>>(a_in, Mm, nullptr, Wt4, nullptr,
                                           mu_g, i2v_g, lae_g, part);
    caps_fin<<<BATCH, 256, 0, stream>>>(part, bu, ba, mu_g, i2v_g, lae_g, 0.012f, nullptr);
    // it 2
    caps_main<1><<<grid, blk, 0, stream>>>(a_in, Mm, nullptr, Wt4, nullptr,
                                           mu_g, i2v_g, lae_g, part);
    caps_fin<<<BATCH, 256, 0, stream>>>(part, bu, ba, mu_g, i2v_g, lae_g, 0.0144f, out);
}

// Round 12
// 173.441 us; speedup vs baseline: 1.2442x; 1.2442x over previous
//
#include <hip/hip_runtime.h>
#include <math.h>

#define IN_UNITS 1152
#define OUT_UNITS 32
#define BATCH 64
#define NCHK 48            // i-chunks; 48%8==0 -> chunk c on XCD c%8
#define IPB 24             // i's per chunk
#define NG 3               // i-groups per chunk (8 i x 32 o per group)
#define PREC 33            // values per (chunk,o): S, mu[16], v2[16]
#define PBLK (PREC*OUT_UNITS)   // 1056 floats, layout [j][o] (o-minor)

// thread layout: t = il*32 + o (o=t&31, il=t>>5); lanes l,l^32 share o.
// MODE 0: stats under R = a/32; reads ORIGINAL W[i][o][ch] (4 y-loads per
//         (i,o) hit one 64B line -> L1 absorbs; one-time cost).
// MODE 1: R-update (softmax over o) + stats; reads transposed Wt (coalesced).
template<int MODE>
__global__ __launch_bounds__(256, 4) void caps_main(
    const float* __restrict__ a_in, const float* __restrict__ Mm,
    const float* __restrict__ Wg, const float4* __restrict__ Wt4,
    const float* __restrict__ mu_g, const float* __restrict__ i2v_g,
    const float* __restrict__ lae_g,
    float* __restrict__ part)
{
    const int t = threadIdx.x, o = t & 31, il = t >> 5, wv = t >> 6, lane = t & 63;
    const int c = blockIdx.x, b = blockIdx.y, i0 = c*IPB;

    __shared__ float sRed[4][PBLK];   // 16.9 KB

    // per-thread routing state for this o, in registers (no LDS, no barrier)
    float rmu[16], ri2[16], lae = 0.f;
    if (MODE) {
        #pragma unroll
        for (int k = 0; k < 16; ++k) {
            rmu[k] = mu_g[b*512 + k*32 + o];    // coalesced across o
            ri2[k] = i2v_g[b*512 + k*32 + o];
        }
        lae = lae_g[b*32 + o];                  // log a + log eff
    }

    // MODE0: original layout, float4 idx i*128 + o*4 + y (y contiguous, 1 line)
    // MODE1: transposed,      float4 idx i*128 + y*32 + o (lanes contiguous)
    const float4* wbase = MODE ? (Wt4 + (i0 + il)*128 + o)
                               : ((const float4*)Wg + (i0 + il)*128 + o*4);
    const float4* mbase = (const float4*)Mm + (b*IN_UNITS + i0 + il)*4;  // +g*32 +x
    const float*  abase = a_in + b*IN_UNITS + i0 + il;          // +g*8

    float pS = 0.f, pmu[16], pv2[16];
    #pragma unroll
    for (int k = 0; k < 16; ++k) { pmu[k] = 0.f; pv2[k] = 0.f; }

    #pragma unroll
    for (int g = 0; g < NG; ++g) {
        float w[16];
        #pragma unroll
        for (int y = 0; y < 4; ++y)
            *(float4*)&w[y*4] = wbase[g*1024 + (MODE ? y*32 : y)];
        float Mr[16];   // 64B row broadcast to 32 lanes via L1
        #pragma unroll
        for (int x = 0; x < 4; ++x) *(float4*)&Mr[x*4] = mbase[g*32 + x];
        const float a_val = abase[g*8];

        float v[16];
        #pragma unroll
        for (int x = 0; x < 4; ++x)
            #pragma unroll
            for (int z = 0; z < 4; ++z) {
                float acc = 0.f;
                #pragma unroll
                for (int y = 0; y < 4; ++y)
                    acc = fmaf(Mr[x*4 + y], w[y*4 + z], acc);
                v[x*4 + z] = acc;
            }

        float wgt;
        if (MODE == 0) {
            wgt = a_val * (1.0f/32.0f);          // R0 = 1/32
        } else {
            float ex0 = 0.f, ex1 = 0.f;
            #pragma unroll
            for (int k = 0; k < 16; k += 2) {
                float d0 = v[k]   - rmu[k];
                float d1 = v[k+1] - rmu[k+1];
                ex0 = fmaf(d0*d0, ri2[k],   ex0);
                ex1 = fmaf(d1*d1, ri2[k+1], ex1);
            }
            float e = __expf(lae - (ex0 + ex1)); // a*eff*exp(exponent)
            float s = e;
            #pragma unroll
            for (int m = 16; m >= 1; m >>= 1) s += __shfl_xor(s, m);
            wgt = (e / s) * a_val;               // R over o, * input_a
        }

        pS += wgt;
        #pragma unroll
        for (int k = 0; k < 16; ++k) {
            pmu[k] = fmaf(wgt, v[k], pmu[k]);
            pv2[k] = fmaf(wgt*v[k], v[k], pv2[k]);
        }
    }

    // lanes l <-> l^32 share o
    pS += __shfl_xor(pS, 32);
    #pragma unroll
    for (int k = 0; k < 16; ++k) {
        pmu[k] += __shfl_xor(pmu[k], 32);
        pv2[k] += __shfl_xor(pv2[k], 32);
    }
    if (lane < 32) {   // [j][o] layout: conflict-free, coalesced downstream
        float* r = &sRed[wv][0];
        r[o] = pS;
        #pragma unroll
        for (int k = 0; k < 16; ++k) {
            r[(1+k)*32 + o]  = pmu[k];
            r[(17+k)*32 + o] = pv2[k];
        }
    }
    __syncthreads();
    float* dst = part + (b*NCHK + c)*PBLK;
    for (int idx = t; idx < PBLK; idx += 256)
        dst[idx] = sRed[0][idx] + sRed[1][idx] + sRed[2][idx] + sRed[3][idx];
}

// finalize: block b (<64) reduces b's 48 chunk-partials (seg handles 6).
// Blocks >= 64 (present only in fin0's grid=128) transpose W -> Wt and exit.
__global__ __launch_bounds__(256) void caps_fin(
    const float* __restrict__ part,
    const float* __restrict__ beta_u, const float* __restrict__ beta_a,
    float* __restrict__ mu_g, float* __restrict__ i2v_g, float* __restrict__ lae_g,
    float lamb, float* __restrict__ out,
    const float4* __restrict__ Wg4, float4* __restrict__ Wt4)
{
    const int bx = blockIdx.x;
    if (bx >= BATCH) {   // transpose tail: Wt[i][y][o][z] <- W[i][o][y*4+z]
        const int tid = (bx - BATCH)*256 + threadIdx.x;   // 0..16383
        #pragma unroll
        for (int j = 0; j < 9; ++j) {
            const int f = j*16384 + tid;          // 147456 = 1152*128 float4s
            const int i = f >> 7, y = (f >> 5) & 3, o = f & 31;
            Wt4[f] = Wg4[i*128 + o*4 + y];        // coalesced store
        }
        return;
    }
    const int b = bx;
    const int t = threadIdx.x;
    const int o = t & 31;
    const int seg = t >> 5;

    float S = 0.f, m[16], q[16];
    #pragma unroll
    for (int k = 0; k < 16; ++k) { m[k] = 0.f; q[k] = 0.f; }
    #pragma unroll
    for (int cc = 0; cc < 6; ++cc) {
        const float* p = part + (b*NCHK + seg + cc*8)*PBLK;
        S += p[o];
        #pragma unroll
        for (int k = 0; k < 16; ++k) {
            m[k] += p[(1+k)*32 + o];
            q[k] += p[(17+k)*32 + o];
        }
    }

    __shared__ float sF[8][PBLK];
    {
        float* r = &sF[seg][0];
        r[o] = S;
        #pragma unroll
        for (int k = 0; k < 16; ++k) { r[(1+k)*32+o] = m[k]; r[(17+k)*32+o] = q[k]; }
    }
    __syncthreads();
    if (t < 32) {
        #pragma unroll
        for (int s = 1; s < 8; ++s) {
            const float* r = &sF[s][0];
            S += r[o];
            #pragma unroll
            for (int k = 0; k < 16; ++k) { m[k] += r[(1+k)*32+o]; q[k] += r[(17+k)*32+o]; }
        }
        const float invS = 1.f / S;
        float mu[16], logvarsum = 0.f;
        #pragma unroll
        for (int k = 0; k < 16; ++k) {
            mu[k] = m[k] * invS;
            float vv = q[k]*invS - mu[k]*mu[k];   // E[v^2] - mu^2
            vv = fmaxf(vv, 1e-30f);
            q[k] = vv;                            // var
            logvarsum += logf(vv);
        }
        const float cost = S * (16.f*beta_u[o] + 0.5f*logvarsum);
        const float x = lamb * (beta_a[o] - cost);
        const float log_a = (x >= 0.f) ? -log1pf(expf(-x)) : (x - log1pf(expf(x)));
        const float LOG2PI = 1.8378770664093453f;
        const float logeff = 16.f*LOG2PI + logvarsum;

        const int tid = b*32 + o;
        lae_g[tid] = log_a + logeff;
        #pragma unroll
        for (int k = 0; k < 16; ++k) {
            mu_g[b*512 + k*32 + o]  = mu[k];
            i2v_g[b*512 + k*32 + o] = 0.5f / q[k];
        }
        if (out) {
            out[tid] = 1.f / (1.f + expf(-x));                      // a (64,32)
            #pragma unroll
            for (int k = 0; k < 16; ++k)
                out[BATCH*OUT_UNITS + tid*16 + k] = mu[k];          // mu (64,32,16)
        }
    }
}

extern "C" void kernel_launch(void* const* d_in, const int* in_sizes, int n_in,
                              void* d_out, int out_size, void* d_ws, size_t ws_size,
                              hipStream_t stream)
{
    const float* a_in = (const float*)d_in[0];
    const float* Mm   = (const float*)d_in[1];
    const float* Wg   = (const float*)d_in[2];
    const float* bu   = (const float*)d_in[3];
    const float* ba   = (const float*)d_in[4];
    float* out = (float*)d_out;

    char* ws = (char*)d_ws;
    size_t off = 0;
    float* part  = (float*)(ws + off); off += (size_t)BATCH*NCHK*PBLK*sizeof(float);
    float* mu_g  = (float*)(ws + off); off += (size_t)BATCH*512*sizeof(float);
    float* i2v_g = (float*)(ws + off); off += (size_t)BATCH*512*sizeof(float);
    float* lae_g = (float*)(ws + off); off += (size_t)BATCH*32*sizeof(float);
    float* Wt    = (float*)(ws + off); off += (size_t)IN_UNITS*OUT_UNITS*16*sizeof(float);

    dim3 grid(NCHK, BATCH), blk(256);
    const float4* Wt4 = (const float4*)Wt;
    const float4* Wg4 = (const float4*)Wg;

    // it 0: stats under R = a/32 (original W layout)
    caps_main<0><<<grid, blk, 0, stream>>>(a_in, Mm, Wg, nullptr,
                                           nullptr, nullptr, nullptr, part);
    // fin0 + transpose tail (blocks 64..127)
    caps_fin<<<128, 256, 0, stream>>>(part, bu, ba, mu_g, i2v_g, lae_g,
                                      0.01f, nullptr, Wg4, (float4*)Wt);
    // it 1
    caps_main<1><<<grid, blk, 0, stream>>>(a_in, Mm, nullptr, Wt4,
                                           mu_g, i2v_g, lae_g, part);
    caps_fin<<<BATCH, 256, 0, stream>>>(part, bu, ba, mu_g, i2v_g, lae_g,
                                        0.012f, nullptr, nullptr, nullptr);
    // it 2
    caps_main<1><<<grid, blk, 0, stream>>>(a_in, Mm, nullptr, Wt4,
                                           mu_g, i2v_g, lae_g, part);
    caps_fin<<<BATCH, 256, 0, stream>>>(part, bu, ba, mu_g, i2v_g, lae_g,
                                        0.0144f, out, nullptr, nullptr);
}

// Round 13
// 79.128 us; speedup vs baseline: 2.7270x; 2.1919x over previous
//
#include <hip/hip_runtime.h>
#include <math.h>

#define IN_UNITS 1152
#define OUT_UNITS 32
#define BATCH 64
#define NCHK 24            // i-chunks; 24%8==0 -> chunk c on XCD c%8
#define IPB 48             // i's per chunk
#define NG 6               // i-groups per chunk (8 i x 32 o per group)
#define PREC 33            // values per (chunk,o): S, mu[16], v2[16]
#define PBLK (PREC*OUT_UNITS)   // 1056 floats, layout [j][o] (o-minor)

// W[i][o][ch] -> Wt[i][y][o][z] (ch=y*4+z). Output-coalesced one-time copy.
// (Paying the 32-line gather ONCE here; R2/R12 proved paying it in the main
//  loop costs 40+ us per dispatch.)
__global__ __launch_bounds__(256) void w_transpose(
    const float* __restrict__ W, float* __restrict__ Wt)
{
    const int gid = blockIdx.x*256 + threadIdx.x;   // 1152*512
    const int i = gid >> 9, rem = gid & 511;
    const int y = rem >> 7, o = (rem >> 2) & 31, z = rem & 3;
    Wt[gid] = W[i*512 + o*16 + y*4 + z];
}

// thread layout: t = il*32 + o (o=t&31, il=t>>5); lanes l,l^32 share o.
// MODE 0: stats under R = a/32.  MODE 1: R-update (softmax over o) + stats.
// Proven-safe code shape: reg-resident routing state, no max-sub softmax,
// 16B/lane coalesced W loads, (256,4) bounds -> 124 VGPR, no spill.
template<int MODE>
__global__ __launch_bounds__(256, 4) void caps_main(
    const float* __restrict__ a_in, const float* __restrict__ Mm,
    const float4* __restrict__ Wt4,
    const float* __restrict__ mu_g, const float* __restrict__ i2v_g,
    const float* __restrict__ lae_g,
    float* __restrict__ part)
{
    const int t = threadIdx.x, o = t & 31, il = t >> 5, wv = t >> 6, lane = t & 63;
    const int c = blockIdx.x, b = blockIdx.y, i0 = c*IPB;

    __shared__ float sRed[4][PBLK];   // 16.9 KB

    // per-thread routing state for this o, in registers (no LDS, no barrier)
    float rmu[16], ri2[16], lae = 0.f;
    if (MODE) {
        #pragma unroll
        for (int k = 0; k < 16; ++k) {
            rmu[k] = mu_g[b*512 + k*32 + o];    // coalesced across o
            ri2[k] = i2v_g[b*512 + k*32 + o];
        }
        lae = lae_g[b*32 + o];                  // log a + log eff
    }

    const float4* wbase = Wt4 + (i0 + il)*128 + o;              // +g*1024 +y*32
    const float4* mbase = (const float4*)Mm + (b*IN_UNITS + i0 + il)*4;  // +g*32 +x
    const float*  abase = a_in + b*IN_UNITS + i0 + il;          // +g*8

    float pS = 0.f, pmu[16], pv2[16];
    #pragma unroll
    for (int k = 0; k < 16; ++k) { pmu[k] = 0.f; pv2[k] = 0.f; }

    #pragma unroll
    for (int g = 0; g < NG; ++g) {
        float w[16];
        #pragma unroll
        for (int y = 0; y < 4; ++y) *(float4*)&w[y*4] = wbase[g*1024 + y*32];
        float Mr[16];   // 64B row broadcast to 32 lanes via L1
        #pragma unroll
        for (int x = 0; x < 4; ++x) *(float4*)&Mr[x*4] = mbase[g*32 + x];
        const float a_val = abase[g*8];

        float v[16];
        #pragma unroll
        for (int x = 0; x < 4; ++x)
            #pragma unroll
            for (int z = 0; z < 4; ++z) {
                float acc = 0.f;
                #pragma unroll
                for (int y = 0; y < 4; ++y)
                    acc = fmaf(Mr[x*4 + y], w[y*4 + z], acc);
                v[x*4 + z] = acc;
            }

        float wgt;
        if (MODE == 0) {
            wgt = a_val * (1.0f/32.0f);          // R0 = 1/32
        } else {
            // direct (no max-sub), mirrors reference: p = eff*exp(-ex), numer=a*p
            float ex0 = 0.f, ex1 = 0.f;
            #pragma unroll
            for (int k = 0; k < 16; k += 2) {
                float d0 = v[k]   - rmu[k];
                float d1 = v[k+1] - rmu[k+1];
                ex0 = fmaf(d0*d0, ri2[k],   ex0);
                ex1 = fmaf(d1*d1, ri2[k+1], ex1);
            }
            float e = __expf(lae - (ex0 + ex1)); // a*eff*exp(exponent)
            float s = e;
            #pragma unroll
            for (int m = 16; m >= 1; m >>= 1) s += __shfl_xor(s, m);
            wgt = (e / s) * a_val;               // R over o, * input_a
        }

        pS += wgt;
        #pragma unroll
        for (int k = 0; k < 16; ++k) {
            pmu[k] = fmaf(wgt, v[k], pmu[k]);
            pv2[k] = fmaf(wgt*v[k], v[k], pv2[k]);
        }
    }

    // lanes l <-> l^32 share o
    pS += __shfl_xor(pS, 32);
    #pragma unroll
    for (int k = 0; k < 16; ++k) {
        pmu[k] += __shfl_xor(pmu[k], 32);
        pv2[k] += __shfl_xor(pv2[k], 32);
    }
    if (lane < 32) {   // [j][o] layout: conflict-free, coalesced downstream
        float* r = &sRed[wv][0];
        r[o] = pS;
        #pragma unroll
        for (int k = 0; k < 16; ++k) {
            r[(1+k)*32 + o]  = pmu[k];
            r[(17+k)*32 + o] = pv2[k];
        }
    }
    __syncthreads();
    float* dst = part + (b*NCHK + c)*PBLK;
    for (int idx = t; idx < PBLK; idx += 256)
        dst[idx] = sRed[0][idx] + sRed[1][idx] + sRed[2][idx] + sRed[3][idx];
}

// finalize: one block per b reduces its 24 chunk-partials (seg handles 3)
__global__ __launch_bounds__(256) void caps_fin(
    const float* __restrict__ part,
    const float* __restrict__ beta_u, const float* __restrict__ beta_a,
    float* __restrict__ mu_g, float* __restrict__ i2v_g, float* __restrict__ lae_g,
    float lamb, float* __restrict__ out)
{
    const int b = blockIdx.x;
    const int t = threadIdx.x;
    const int o = t & 31;
    const int seg = t >> 5;

    float S = 0.f, m[16], q[16];
    #pragma unroll
    for (int k = 0; k < 16; ++k) { m[k] = 0.f; q[k] = 0.f; }
    #pragma unroll
    for (int cc = 0; cc < 3; ++cc) {
        const float* p = part + (b*NCHK + seg + cc*8)*PBLK;
        S += p[o];
        #pragma unroll
        for (int k = 0; k < 16; ++k) {
            m[k] += p[(1+k)*32 + o];
            q[k] += p[(17+k)*32 + o];
        }
    }

    __shared__ float sF[8][PBLK];
    {
        float* r = &sF[seg][0];
        r[o] = S;
        #pragma unroll
        for (int k = 0; k < 16; ++k) { r[(1+k)*32+o] = m[k]; r[(17+k)*32+o] = q[k]; }
    }
    __syncthreads();
    if (t < 32) {
        #pragma unroll
        for (int s = 1; s < 8; ++s) {
            const float* r = &sF[s][0];
            S += r[o];
            #pragma unroll
            for (int k = 0; k < 16; ++k) { m[k] += r[(1+k)*32+o]; q[k] += r[(17+k)*32+o]; }
        }
        const float invS = 1.f / S;
        float mu[16], logvarsum = 0.f;
        #pragma unroll
        for (int k = 0; k < 16; ++k) {
            mu[k] = m[k] * invS;
            float vv = q[k]*invS - mu[k]*mu[k];   // E[v^2] - mu^2
            vv = fmaxf(vv, 1e-30f);
            q[k] = vv;                            // var
            logvarsum += logf(vv);
        }
        const float cost = S * (16.f*beta_u[o] + 0.5f*logvarsum);
        const float x = lamb * (beta_a[o] - cost);
        const float log_a = (x >= 0.f) ? -log1pf(expf(-x)) : (x - log1pf(expf(x)));
        const float LOG2PI = 1.8378770664093453f;
        const float logeff = 16.f*LOG2PI + logvarsum;

        const int tid = b*32 + o;
        lae_g[tid] = log_a + logeff;
        #pragma unroll
        for (int k = 0; k < 16; ++k) {
            mu_g[b*512 + k*32 + o]  = mu[k];
            i2v_g[b*512 + k*32 + o] = 0.5f / q[k];
        }
        if (out) {
            out[tid] = 1.f / (1.f + expf(-x));                      // a (64,32)
            #pragma unroll
            for (int k = 0; k < 16; ++k)
                out[BATCH*OUT_UNITS + tid*16 + k] = mu[k];          // mu (64,32,16)
        }
    }
}

extern "C" void kernel_launch(void* const* d_in, const int* in_sizes, int n_in,
                              void* d_out, int out_size, void* d_ws, size_t ws_size,
                              hipStream_t stream)
{
    const float* a_in = (const float*)d_in[0];
    const float* Mm   = (const float*)d_in[1];
    const float* Wg   = (const float*)d_in[2];
    const float* bu   = (const float*)d_in[3];
    const float* ba   = (const float*)d_in[4];
    float* out = (float*)d_out;

    char* ws = (char*)d_ws;
    size_t off = 0;
    float* part  = (float*)(ws + off); off += (size_t)BATCH*NCHK*PBLK*sizeof(float);
    float* mu_g  = (float*)(ws + off); off += (size_t)BATCH*512*sizeof(float);
    float* i2v_g = (float*)(ws + off); off += (size_t)BATCH*512*sizeof(float);
    float* lae_g = (float*)(ws + off); off += (size_t)BATCH*32*sizeof(float);
    float* Wt    = (float*)(ws + off); off += (size_t)IN_UNITS*OUT_UNITS*16*sizeof(float);

    dim3 grid(NCHK, BATCH), blk(256);
    const float4* Wt4 = (const float4*)Wt;

    w_transpose<<<IN_UNITS*512/256, 256, 0, stream>>>(Wg, Wt);
    caps_main<0><<<grid, blk, 0, stream>>>(a_in, Mm, Wt4, nullptr, nullptr, nullptr, part);
    caps_fin<<<BATCH, 256, 0, stream>>>(part, bu, ba, mu_g, i2v_g, lae_g, 0.01f, nullptr);
    caps_main<1><<<grid, blk, 0, stream>>>(a_in, Mm, Wt4, mu_g, i2v_g, lae_g, part);
    caps_fin<<<BATCH, 256, 0, stream>>>(part, bu, ba, mu_g, i2v_g, lae_g, 0.012f, nullptr);
    caps_main<1><<<grid, blk, 0, stream>>>(a_in, Mm, Wt4, mu_g, i2v_g, lae_g, part);
    caps_fin<<<BATCH, 256, 0, stream>>>(part, bu, ba, mu_g, i2v_g, lae_g, 0.0144f, out);
}

// Round 14
// 73.782 us; speedup vs baseline: 2.9246x; 1.0725x over previous
//
#include <hip/hip_runtime.h>
#include <math.h>

#define IN_UNITS 1152
#define OUT_UNITS 32
#define BATCH 64
#define NCHK 16            // i-chunks; 16%8==0 -> chunk c on XCD c%8
                           // grid (16,64) = 1024 blocks = EXACTLY one generation
                           // at 4 blocks/CU (no ragged tail; R13 had 1.5 gens)
#define IPB 72             // i's per chunk
#define NG 9               // i-groups per chunk (8 i x 32 o per group)
#define PREC 33            // values per (chunk,o): S, mu[16], v2[16]
#define PBLK (PREC*OUT_UNITS)   // 1056 floats, layout [j][o] (o-minor)

// W[i][o][ch] -> Wt[i][y][o][z] (ch=y*4+z). Output-coalesced one-time copy.
// (Paying the 32-line gather ONCE here; R2/R12 proved paying it in the main
//  loop costs 40+ us per dispatch.)
__global__ __launch_bounds__(256) void w_transpose(
    const float* __restrict__ W, float* __restrict__ Wt)
{
    const int gid = blockIdx.x*256 + threadIdx.x;   // 1152*512
    const int i = gid >> 9, rem = gid & 511;
    const int y = rem >> 7, o = (rem >> 2) & 31, z = rem & 3;
    Wt[gid] = W[i*512 + o*16 + y*4 + z];
}

// thread layout: t = il*32 + o (o=t&31, il=t>>5); lanes l,l^32 share o.
// MODE 0: stats under R = a/32.  MODE 1: R-update (softmax over o) + stats.
// Proven-safe code shape: reg-resident routing state, no max-sub softmax,
// 16B/lane coalesced W loads, (256,4) bounds -> ~124 VGPR, no spill.
template<int MODE>
__global__ __launch_bounds__(256, 4) void caps_main(
    const float* __restrict__ a_in, const float* __restrict__ Mm,
    const float4* __restrict__ Wt4,
    const float* __restrict__ mu_g, const float* __restrict__ i2v_g,
    const float* __restrict__ lae_g,
    float* __restrict__ part)
{
    const int t = threadIdx.x, o = t & 31, il = t >> 5, wv = t >> 6, lane = t & 63;
    const int c = blockIdx.x, b = blockIdx.y, i0 = c*IPB;

    __shared__ float sRed[4][PBLK];   // 16.9 KB

    // per-thread routing state for this o, in registers (no LDS, no barrier)
    float rmu[16], ri2[16], lae = 0.f;
    if (MODE) {
        #pragma unroll
        for (int k = 0; k < 16; ++k) {
            rmu[k] = mu_g[b*512 + k*32 + o];    // coalesced across o
            ri2[k] = i2v_g[b*512 + k*32 + o];
        }
        lae = lae_g[b*32 + o];                  // log a + log eff
    }

    const float4* wbase = Wt4 + (i0 + il)*128 + o;              // +g*1024 +y*32
    const float4* mbase = (const float4*)Mm + (b*IN_UNITS + i0 + il)*4;  // +g*32 +x
    const float*  abase = a_in + b*IN_UNITS + i0 + il;          // +g*8

    float pS = 0.f, pmu[16], pv2[16];
    #pragma unroll
    for (int k = 0; k < 16; ++k) { pmu[k] = 0.f; pv2[k] = 0.f; }

    #pragma unroll
    for (int g = 0; g < NG; ++g) {
        float w[16];
        #pragma unroll
        for (int y = 0; y < 4; ++y) *(float4*)&w[y*4] = wbase[g*1024 + y*32];
        float Mr[16];   // 64B row broadcast to 32 lanes via L1
        #pragma unroll
        for (int x = 0; x < 4; ++x) *(float4*)&Mr[x*4] = mbase[g*32 + x];
        const float a_val = abase[g*8];

        float v[16];
        #pragma unroll
        for (int x = 0; x < 4; ++x)
            #pragma unroll
            for (int z = 0; z < 4; ++z) {
                float acc = 0.f;
                #pragma unroll
                for (int y = 0; y < 4; ++y)
                    acc = fmaf(Mr[x*4 + y], w[y*4 + z], acc);
                v[x*4 + z] = acc;
            }

        float wgt;
        if (MODE == 0) {
            wgt = a_val * (1.0f/32.0f);          // R0 = 1/32
        } else {
            // direct (no max-sub), mirrors reference: p = eff*exp(-ex), numer=a*p
            float ex0 = 0.f, ex1 = 0.f;
            #pragma unroll
            for (int k = 0; k < 16; k += 2) {
                float d0 = v[k]   - rmu[k];
                float d1 = v[k+1] - rmu[k+1];
                ex0 = fmaf(d0*d0, ri2[k],   ex0);
                ex1 = fmaf(d1*d1, ri2[k+1], ex1);
            }
            float e = __expf(lae - (ex0 + ex1)); // a*eff*exp(exponent)
            float s = e;
            #pragma unroll
            for (int m = 16; m >= 1; m >>= 1) s += __shfl_xor(s, m);
            wgt = (e / s) * a_val;               // R over o, * input_a
        }

        pS += wgt;
        #pragma unroll
        for (int k = 0; k < 16; ++k) {
            pmu[k] = fmaf(wgt, v[k], pmu[k]);
            pv2[k] = fmaf(wgt*v[k], v[k], pv2[k]);
        }
    }

    // lanes l <-> l^32 share o
    pS += __shfl_xor(pS, 32);
    #pragma unroll
    for (int k = 0; k < 16; ++k) {
        pmu[k] += __shfl_xor(pmu[k], 32);
        pv2[k] += __shfl_xor(pv2[k], 32);
    }
    if (lane < 32) {   // [j][o] layout: conflict-free, coalesced downstream
        float* r = &sRed[wv][0];
        r[o] = pS;
        #pragma unroll
        for (int k = 0; k < 16; ++k) {
            r[(1+k)*32 + o]  = pmu[k];
            r[(17+k)*32 + o] = pv2[k];
        }
    }
    __syncthreads();
    float* dst = part + (b*NCHK + c)*PBLK;
    for (int idx = t; idx < PBLK; idx += 256)
        dst[idx] = sRed[0][idx] + sRed[1][idx] + sRed[2][idx] + sRed[3][idx];
}

// finalize: one block per b reduces its 16 chunk-partials (seg handles 2)
__global__ __launch_bounds__(256) void caps_fin(
    const float* __restrict__ part,
    const float* __restrict__ beta_u, const float* __restrict__ beta_a,
    float* __restrict__ mu_g, float* __restrict__ i2v_g, float* __restrict__ lae_g,
    float lamb, float* __restrict__ out)
{
    const int b = blockIdx.x;
    const int t = threadIdx.x;
    const int o = t & 31;
    const int seg = t >> 5;

    float S = 0.f, m[16], q[16];
    #pragma unroll
    for (int k = 0; k < 16; ++k) { m[k] = 0.f; q[k] = 0.f; }
    #pragma unroll
    for (int cc = 0; cc < 2; ++cc) {
        const float* p = part + (b*NCHK + seg + cc*8)*PBLK;
        S += p[o];
        #pragma unroll
        for (int k = 0; k < 16; ++k) {
            m[k] += p[(1+k)*32 + o];
            q[k] += p[(17+k)*32 + o];
        }
    }

    __shared__ float sF[8][PBLK];
    {
        float* r = &sF[seg][0];
        r[o] = S;
        #pragma unroll
        for (int k = 0; k < 16; ++k) { r[(1+k)*32+o] = m[k]; r[(17+k)*32+o] = q[k]; }
    }
    __syncthreads();
    if (t < 32) {
        #pragma unroll
        for (int s = 1; s < 8; ++s) {
            const float* r = &sF[s][0];
            S += r[o];
            #pragma unroll
            for (int k = 0; k < 16; ++k) { m[k] += r[(1+k)*32+o]; q[k] += r[(17+k)*32+o]; }
        }
        const float invS = 1.f / S;
        float mu[16], logvarsum = 0.f;
        #pragma unroll
        for (int k = 0; k < 16; ++k) {
            mu[k] = m[k] * invS;
            float vv = q[k]*invS - mu[k]*mu[k];   // E[v^2] - mu^2
            vv = fmaxf(vv, 1e-30f);
            q[k] = vv;                            // var
            logvarsum += logf(vv);
        }
        const float cost = S * (16.f*beta_u[o] + 0.5f*logvarsum);
        const float x = lamb * (beta_a[o] - cost);
        const float log_a = (x >= 0.f) ? -log1pf(expf(-x)) : (x - log1pf(expf(x)));
        const float LOG2PI = 1.8378770664093453f;
        const float logeff = 16.f*LOG2PI + logvarsum;

        const int tid = b*32 + o;
        lae_g[tid] = log_a + logeff;
        #pragma unroll
        for (int k = 0; k < 16; ++k) {
            mu_g[b*512 + k*32 + o]  = mu[k];
            i2v_g[b*512 + k*32 + o] = 0.5f / q[k];
        }
        if (out) {
            out[tid] = 1.f / (1.f + expf(-x));                      // a (64,32)
            #pragma unroll
            for (int k = 0; k < 16; ++k)
                out[BATCH*OUT_UNITS + tid*16 + k] = mu[k];          // mu (64,32,16)
        }
    }
}

extern "C" void kernel_launch(void* const* d_in, const int* in_sizes, int n_in,
                              void* d_out, int out_size, void* d_ws, size_t ws_size,
                              hipStream_t stream)
{
    const float* a_in = (const float*)d_in[0];
    const float* Mm   = (const float*)d_in[1];
    const float* Wg   = (const float*)d_in[2];
    const float* bu   = (const float*)d_in[3];
    const float* ba   = (const float*)d_in[4];
    float* out = (float*)d_out;

    char* ws = (char*)d_ws;
    size_t off = 0;
    float* part  = (float*)(ws + off); off += (size_t)BATCH*NCHK*PBLK*sizeof(float);
    float* mu_g  = (float*)(ws + off); off += (size_t)BATCH*512*sizeof(float);
    float* i2v_g = (float*)(ws + off); off += (size_t)BATCH*512*sizeof(float);
    float* lae_g = (float*)(ws + off); off += (size_t)BATCH*32*sizeof(float);
    float* Wt    = (float*)(ws + off); off += (size_t)IN_UNITS*OUT_UNITS*16*sizeof(float);

    dim3 grid(NCHK, BATCH), blk(256);
    const float4* Wt4 = (const float4*)Wt;

    w_transpose<<<IN_UNITS*512/256, 256, 0, stream>>>(Wg, Wt);
    caps_main<0><<<grid, blk, 0, stream>>>(a_in, Mm, Wt4, nullptr, nullptr, nullptr, part);
    caps_fin<<<BATCH, 256, 0, stream>>>(part, bu, ba, mu_g, i2v_g, lae_g, 0.01f, nullptr);
    caps_main<1><<<grid, blk, 0, stream>>>(a_in, Mm, Wt4, mu_g, i2v_g, lae_g, part);
    caps_fin<<<BATCH, 256, 0, stream>>>(part, bu, ba, mu_g, i2v_g, lae_g, 0.012f, nullptr);
    caps_main<1><<<grid, blk, 0, stream>>>(a_in, Mm, Wt4, mu_g, i2v_g, lae_g, part);
    caps_fin<<<BATCH, 256, 0, stream>>>(part, bu, ba, mu_g, i2v_g, lae_g, 0.0144f, out);
}